// Round 1
// baseline (505.329 us; speedup 1.0000x reference)
//
#include <hip/hip_runtime.h>

#define NH 4
#define HD 128
#define BS 32
#define STRIDE 16
#define MTILE 64
#define LDA 136   // 128 + 8 bf16 pad (16B) -> row stride 272 B, breaks pow2 bank stride
#define LDB 136

typedef float  floatx4 __attribute__((ext_vector_type(4)));
typedef __bf16 bf16x8  __attribute__((ext_vector_type(8)));
typedef unsigned short u16x8 __attribute__((ext_vector_type(8)));

__device__ __forceinline__ unsigned short f2bf(float f) {
  unsigned u = __builtin_bit_cast(unsigned, f);
  u += 0x7FFFu + ((u >> 16) & 1u);   // round-to-nearest-even (inputs finite)
  return (unsigned short)(u >> 16);
}

// Always-run: writes cu_out prefix sums as float into d_out tail (output 2),
// and (fast path) as ints into ws for the GEMM kernel's row->base lookup.
__global__ void tail_kernel(const int* __restrict__ cu, int num_seqs,
                            float* __restrict__ tail, int* cu_out_ws, int write_ws) {
  if (threadIdx.x == 0) {
    int acc = 0;
    tail[0] = 0.0f;
    if (write_ws) cu_out_ws[0] = 0;
    for (int b = 0; b < num_seqs; ++b) {
      int n = cu[b + 1] - cu[b];
      int ol = (n - BS) / STRIDE;
      acc += ol;
      tail[b + 1] = (float)acc;
      if (write_ws) cu_out_ws[b + 1] = acc;
    }
  }
}

// Pre-transpose + bf16-convert weights into ws as [mat][j][e][d] so that
// per-j B tiles are contiguous 32 KB blocks (coalesced stage, contiguous k for
// MFMA B-fragments). 2 MB total; w is L2-resident so strided reads are cheap.
__global__ void transpose_w(const float* __restrict__ wk, const float* __restrict__ wv,
                            unsigned short* __restrict__ wt) {
  const int per = BS * HD * HD;  // 524288
  for (int t = blockIdx.x * blockDim.x + threadIdx.x; t < 2 * per;
       t += gridDim.x * blockDim.x) {
    int mat = t / per;
    int r = t - mat * per;
    int j = r >> 14;        // 128*128 per j
    int rr = r & 16383;
    int e = rr >> 7;
    int d = rr & 127;
    const float* w = mat ? wv : wk;
    wt[t] = f2bf(w[j * (HD * HD) + d * HD + e]);
  }
}

// Main GEMM: C[m=(o,h)][e] = sum_{j,d} X[base(o)+j, h, d] * W[j*128+d, e]
// M-tile 64 x N 128, K-loop over j (32 iters), 128-wide d slice per iter.
__global__ __launch_bounds__(256) void kvc_gemm(
    const float* __restrict__ kp, const float* __restrict__ vp,
    const unsigned short* __restrict__ wt, const int* __restrict__ cu,
    const int* __restrict__ cu_out, float* __restrict__ out,
    long out_half, int M_total, int num_seqs) {

  __shared__ unsigned short As[MTILE][LDA];  // 17408 B
  __shared__ unsigned short Bs[HD][LDB];     // 34816 B  (Bs[n=e][k=d])

  const int mat = blockIdx.y;
  const float* __restrict__ x = mat ? vp : kp;
  const unsigned short* __restrict__ w = wt + (size_t)mat * (BS * HD * HD);
  float* __restrict__ outp = out + (size_t)mat * out_half;
  const int m0 = blockIdx.x * MTILE;
  const int tid = threadIdx.x;

  // ---- A staging setup: 4 threads per row, 32 floats each
  const int ar = tid >> 2;
  const int aq = tid & 3;
  const int m_g = m0 + ar;
  int tbase = 0;
  if (m_g < M_total) {
    int o = m_g >> 2;
    int b = 0;
    while (b + 1 < num_seqs && o >= cu_out[b + 1]) ++b;
    tbase = cu[b] + (o - cu_out[b]) * STRIDE;
  }
  const int h = m_g & 3;
  const float* aptr = x + ((size_t)tbase * NH + h) * HD + aq * 32;
  unsigned short* as_dst = &As[ar][aq * 32];

  // ---- B staging setup: 2 threads per e-row, 64 bf16 each
  const int br = tid >> 1;
  const int bh = tid & 1;
  const unsigned short* bptr = w + br * HD + bh * 64;
  unsigned short* bs_dst = &Bs[br][bh * 64];

  // ---- fragment addressing (verified 16x16x32 bf16 layouts:
  //      A[m=lane&15][k=quad*8+j], B[k=quad*8+j][n=lane&15],
  //      C/D col=lane&15 row=quad*4+reg)
  const int wid = tid >> 6;
  const int lane = tid & 63;
  const int wm = (wid & 1) * 32;   // wave's m offset (2x2 wave grid)
  const int wn = (wid >> 1) * 64;  // wave's n offset
  const int fl = lane & 15;
  const int fq = lane >> 4;

  floatx4 acc[2][4];
#pragma unroll
  for (int mi = 0; mi < 2; ++mi)
#pragma unroll
    for (int ni = 0; ni < 4; ++ni) acc[mi][ni] = (floatx4){0.f, 0.f, 0.f, 0.f};

  for (int j = 0; j < BS; ++j) {
    __syncthreads();
    // stage A slice: X[tbase+j, h, 0:128] per row, fp32 -> bf16
    const float4* ap = (const float4*)(aptr + (size_t)j * (NH * HD));
    float4 av[8];
#pragma unroll
    for (int i = 0; i < 8; ++i) av[i] = ap[i];
#pragma unroll
    for (int i = 0; i < 4; ++i) {
      u16x8 t;
      t[0] = f2bf(av[2 * i].x);     t[1] = f2bf(av[2 * i].y);
      t[2] = f2bf(av[2 * i].z);     t[3] = f2bf(av[2 * i].w);
      t[4] = f2bf(av[2 * i + 1].x); t[5] = f2bf(av[2 * i + 1].y);
      t[6] = f2bf(av[2 * i + 1].z); t[7] = f2bf(av[2 * i + 1].w);
      *(u16x8*)(as_dst + i * 8) = t;
    }
    // stage B slice: contiguous 32 KB bf16 copy
    const u16x8* bp = (const u16x8*)(bptr + (size_t)j * (HD * HD));
#pragma unroll
    for (int i = 0; i < 8; ++i) *(u16x8*)(bs_dst + i * 8) = bp[i];
    __syncthreads();

#pragma unroll
    for (int k0 = 0; k0 < HD; k0 += 32) {
      bf16x8 af[2], bfr[4];
#pragma unroll
      for (int mi = 0; mi < 2; ++mi)
        af[mi] = *(const bf16x8*)&As[wm + mi * 16 + fl][k0 + fq * 8];
#pragma unroll
      for (int ni = 0; ni < 4; ++ni)
        bfr[ni] = *(const bf16x8*)&Bs[wn + ni * 16 + fl][k0 + fq * 8];
#pragma unroll
      for (int mi = 0; mi < 2; ++mi)
#pragma unroll
        for (int ni = 0; ni < 4; ++ni)
          acc[mi][ni] = __builtin_amdgcn_mfma_f32_16x16x32_bf16(
              af[mi], bfr[ni], acc[mi][ni], 0, 0, 0);
    }
  }

#pragma unroll
  for (int mi = 0; mi < 2; ++mi) {
#pragma unroll
    for (int r = 0; r < 4; ++r) {
      int m_gl = m0 + wm + mi * 16 + fq * 4 + r;
      if (m_gl < M_total) {
        float* orow = outp + (size_t)m_gl * HD + wn + fl;
#pragma unroll
        for (int ni = 0; ni < 4; ++ni) orow[ni * 16] = acc[mi][ni][r];
      }
    }
  }
}

// Correct-but-slow fallback if ws is too small for the weight transpose.
__global__ void kvc_naive(const float* __restrict__ kp, const float* __restrict__ vp,
                          const float* __restrict__ wk, const float* __restrict__ wv,
                          const int* __restrict__ cu, int num_seqs,
                          float* __restrict__ out, long out_half) {
  int o = blockIdx.x, h = blockIdx.y, mat = blockIdx.z;
  int e = threadIdx.x;
  int acc = 0, base = -1;
  for (int b = 0; b < num_seqs; ++b) {
    int n = cu[b + 1] - cu[b];
    int ol = (n - BS) / STRIDE;
    if (o < acc + ol) { base = cu[b] + (o - acc) * STRIDE; break; }
    acc += ol;
  }
  if (base < 0) return;
  const float* x = mat ? vp : kp;
  const float* w = mat ? wv : wk;
  float s = 0.f;
  for (int j = 0; j < BS; ++j)
    for (int d = 0; d < HD; ++d)
      s += x[(size_t)(base + j) * (NH * HD) + h * HD + d] * w[(j * HD + d) * HD + e];
  out[(size_t)mat * out_half + ((size_t)o * NH + h) * HD + e] = s;
}

extern "C" void kernel_launch(void* const* d_in, const int* in_sizes, int n_in,
                              void* d_out, int out_size, void* d_ws, size_t ws_size,
                              hipStream_t stream) {
  const float* kp = (const float*)d_in[0];
  const float* vp = (const float*)d_in[1];
  const float* wk = (const float*)d_in[2];
  const float* wv = (const float*)d_in[3];
  const int* cu = (const int*)d_in[4];
  const int num_seqs = in_sizes[4] - 1;
  float* out = (float*)d_out;

  const long total_out = ((long)out_size - (num_seqs + 1)) / (2L * NH * HD);
  const long out_half = total_out * NH * HD;
  const int M_total = (int)(total_out * NH);
  float* tail = out + 2 * out_half;

  const size_t need_ws = 4096 + (size_t)2 * BS * HD * HD * sizeof(unsigned short);
  if (ws_size >= need_ws) {
    int* cu_out_ws = (int*)d_ws;
    unsigned short* wt = (unsigned short*)((char*)d_ws + 4096);
    tail_kernel<<<1, 64, 0, stream>>>(cu, num_seqs, tail, cu_out_ws, 1);
    transpose_w<<<1024, 256, 0, stream>>>(wk, wv, wt);
    dim3 grid((M_total + MTILE - 1) / MTILE, 2);
    kvc_gemm<<<grid, 256, 0, stream>>>(kp, vp, wt, cu, cu_out_ws, out,
                                       out_half, M_total, num_seqs);
  } else {
    tail_kernel<<<1, 64, 0, stream>>>(cu, num_seqs, tail, nullptr, 0);
    dim3 grid((unsigned)total_out, NH, 2);
    kvc_naive<<<grid, HD, 0, stream>>>(kp, vp, wk, wv, cu, num_seqs, out, out_half);
  }
}

// Round 2
// 402.482 us; speedup vs baseline: 1.2555x; 1.2555x over previous
//
#include <hip/hip_runtime.h>

#define NH 4
#define HD 128
#define BS 32
#define STRIDE 16

typedef float  floatx4 __attribute__((ext_vector_type(4)));
typedef __bf16 bf16x8  __attribute__((ext_vector_type(8)));
typedef unsigned short u16x8 __attribute__((ext_vector_type(8)));

__device__ __forceinline__ unsigned short f2bf(float f) {
  unsigned u = __builtin_bit_cast(unsigned, f);
  u += 0x7FFFu + ((u >> 16) & 1u);   // RTNE (inputs finite)
  return (unsigned short)(u >> 16);
}

// Always-run: writes cu_out prefix sums as float into d_out tail (output 2),
// and (fast path) as ints into ws for the GEMM kernel's row->base lookup.
__global__ void tail_kernel(const int* __restrict__ cu, int num_seqs,
                            float* __restrict__ tail, int* cu_out_ws, int write_ws) {
  if (threadIdx.x == 0) {
    int acc = 0;
    tail[0] = 0.0f;
    if (write_ws) cu_out_ws[0] = 0;
    for (int b = 0; b < num_seqs; ++b) {
      int n = cu[b + 1] - cu[b];
      int ol = (n - BS) / STRIDE;
      acc += ol;
      tail[b + 1] = (float)acc;
      if (write_ws) cu_out_ws[b + 1] = acc;
    }
  }
}

// Weights -> bf16, layout [mat][j][k0][e][d'] (d' = d - 32*k0, 32 per k0).
// A B-fragment read (16 lanes x 16B) is then 1KB fully contiguous.
__global__ void transpose_w(const float* __restrict__ wk, const float* __restrict__ wv,
                            unsigned short* __restrict__ wt) {
  const int per = BS * HD * HD;  // 524288
  for (int t = blockIdx.x * blockDim.x + threadIdx.x; t < 2 * per;
       t += gridDim.x * blockDim.x) {
    int mat = t / per;
    int r = t - mat * per;
    int j  = r >> 14;          // 16384 per j
    int rr = r & 16383;
    int k0 = rr >> 12;         // 4096 per k0
    int r2 = rr & 4095;
    int e  = r2 >> 5;
    int dp = r2 & 31;
    int d  = k0 * 32 + dp;
    const float* w = mat ? wv : wk;
    wt[t] = f2bf(w[j * (HD * HD) + d * HD + e]);
  }
}

// Barrier-free, LDS-free GEMM. Wave tile 16m x 128n, block = 4 waves (64 m).
// A fragments straight from k/v (fp32 -> bf16 in regs, prefetched 1 j ahead);
// B fragments straight from L2-resident transposed weights (1 k0 ahead).
__global__ __launch_bounds__(256, 2) void kvc_gemm(
    const float* __restrict__ kp, const float* __restrict__ vp,
    const unsigned short* __restrict__ wt, const int* __restrict__ cu,
    const int* __restrict__ cu_out, float* __restrict__ out,
    long out_half, int M_total, int num_seqs) {

  const int mat = blockIdx.y;
  const float* __restrict__ x = mat ? vp : kp;
  const unsigned short* __restrict__ w = wt + (size_t)mat * (BS * HD * HD);
  float* __restrict__ outp = out + (size_t)mat * out_half;

  const int tid  = threadIdx.x;
  const int wid  = tid >> 6;
  const int lane = tid & 63;
  const int fl   = lane & 15;        // m-row (A) / e-col (B/C)
  const int fq   = lane >> 4;        // k-octet selector
  const int wm0  = blockIdx.x * 64 + wid * 16;

  // per-lane A row: m -> (o,h) -> token base
  int m  = wm0 + fl;
  int mc = m < M_total ? m : M_total - 1;
  int o = mc >> 2, h = mc & 3;
  int b = 0;
  while (b + 1 < num_seqs && o >= cu_out[b + 1]) ++b;
  const int tbase = cu[b] + (o - cu_out[b]) * STRIDE;
  const float* __restrict__ arow = x + ((size_t)tbase * NH + h) * HD + fq * 8;

  // per-lane B base (shorts): + j*16384 + k0*4096 + ni*512
  const unsigned short* __restrict__ wlane = w + fl * 32 + fq * 8;

  floatx4 acc[8];
#pragma unroll
  for (int ni = 0; ni < 8; ++ni) acc[ni] = (floatx4){0.f, 0.f, 0.f, 0.f};

  float4 a_cur[8];
#pragma unroll
  for (int k0 = 0; k0 < 4; ++k0) {
    a_cur[2 * k0]     = *(const float4*)(arow + k0 * 32);
    a_cur[2 * k0 + 1] = *(const float4*)(arow + k0 * 32 + 4);
  }
  u16x8 bcur[8];
#pragma unroll
  for (int ni = 0; ni < 8; ++ni) bcur[ni] = *(const u16x8*)(wlane + ni * 512);

  for (int j = 0; j < BS; ++j) {
    // prefetch A(j+1) — in flight across all of j's MFMAs
    const int jn = (j + 1 < BS) ? j + 1 : j;
    const float* arn = arow + (size_t)jn * (NH * HD);
    float4 a_nxt[8];
#pragma unroll
    for (int k0 = 0; k0 < 4; ++k0) {
      a_nxt[2 * k0]     = *(const float4*)(arn + k0 * 32);
      a_nxt[2 * k0 + 1] = *(const float4*)(arn + k0 * 32 + 4);
    }

#pragma unroll
    for (int k0 = 0; k0 < 4; ++k0) {
      // prefetch next B frag set (L2-resident)
      const int nj  = (k0 == 3) ? jn : j;
      const int nk0 = (k0 == 3) ? 0 : k0 + 1;
      const unsigned short* wb = wlane + (size_t)nj * 16384 + nk0 * 4096;
      u16x8 bnxt[8];
#pragma unroll
      for (int ni = 0; ni < 8; ++ni) bnxt[ni] = *(const u16x8*)(wb + ni * 512);

      // convert A k0-slice fp32 -> bf16x8
      const float4 lo = a_cur[2 * k0], hi = a_cur[2 * k0 + 1];
      u16x8 at;
      at[0] = f2bf(lo.x); at[1] = f2bf(lo.y); at[2] = f2bf(lo.z); at[3] = f2bf(lo.w);
      at[4] = f2bf(hi.x); at[5] = f2bf(hi.y); at[6] = f2bf(hi.z); at[7] = f2bf(hi.w);
      const bf16x8 af = __builtin_bit_cast(bf16x8, at);

#pragma unroll
      for (int ni = 0; ni < 8; ++ni)
        acc[ni] = __builtin_amdgcn_mfma_f32_16x16x32_bf16(
            af, __builtin_bit_cast(bf16x8, bcur[ni]), acc[ni], 0, 0, 0);
#pragma unroll
      for (int ni = 0; ni < 8; ++ni) bcur[ni] = bnxt[ni];
    }
#pragma unroll
    for (int i = 0; i < 8; ++i) a_cur[i] = a_nxt[i];
  }

  // C/D: col = lane&15 (=fl), row = fq*4 + reg
#pragma unroll
  for (int ni = 0; ni < 8; ++ni) {
#pragma unroll
    for (int r = 0; r < 4; ++r) {
      const int mg = wm0 + fq * 4 + r;
      if (mg < M_total) outp[(size_t)mg * HD + ni * 16 + fl] = acc[ni][r];
    }
  }
}

// Correct-but-slow fallback if ws is too small for the weight transpose.
__global__ void kvc_naive(const float* __restrict__ kp, const float* __restrict__ vp,
                          const float* __restrict__ wk, const float* __restrict__ wv,
                          const int* __restrict__ cu, int num_seqs,
                          float* __restrict__ out, long out_half) {
  int o = blockIdx.x, h = blockIdx.y, mat = blockIdx.z;
  int e = threadIdx.x;
  int acc = 0, base = -1;
  for (int b = 0; b < num_seqs; ++b) {
    int n = cu[b + 1] - cu[b];
    int ol = (n - BS) / STRIDE;
    if (o < acc + ol) { base = cu[b] + (o - acc) * STRIDE; break; }
    acc += ol;
  }
  if (base < 0) return;
  const float* x = mat ? vp : kp;
  const float* w = mat ? wv : wk;
  float s = 0.f;
  for (int j = 0; j < BS; ++j)
    for (int d = 0; d < HD; ++d)
      s += x[(size_t)(base + j) * (NH * HD) + h * HD + d] * w[(j * HD + d) * HD + e];
  out[(size_t)mat * out_half + ((size_t)o * NH + h) * HD + e] = s;
}

extern "C" void kernel_launch(void* const* d_in, const int* in_sizes, int n_in,
                              void* d_out, int out_size, void* d_ws, size_t ws_size,
                              hipStream_t stream) {
  const float* kp = (const float*)d_in[0];
  const float* vp = (const float*)d_in[1];
  const float* wk = (const float*)d_in[2];
  const float* wv = (const float*)d_in[3];
  const int* cu = (const int*)d_in[4];
  const int num_seqs = in_sizes[4] - 1;
  float* out = (float*)d_out;

  const long total_out = ((long)out_size - (num_seqs + 1)) / (2L * NH * HD);
  const long out_half = total_out * NH * HD;
  const int M_total = (int)(total_out * NH);
  float* tail = out + 2 * out_half;

  const size_t need_ws = 4096 + (size_t)2 * BS * HD * HD * sizeof(unsigned short);
  if (ws_size >= need_ws) {
    int* cu_out_ws = (int*)d_ws;
    unsigned short* wt = (unsigned short*)((char*)d_ws + 4096);
    tail_kernel<<<1, 64, 0, stream>>>(cu, num_seqs, tail, cu_out_ws, 1);
    transpose_w<<<1024, 256, 0, stream>>>(wk, wv, wt);
    dim3 grid((M_total + 63) / 64, 2);
    kvc_gemm<<<grid, 256, 0, stream>>>(kp, vp, wt, cu, cu_out_ws, out,
                                       out_half, M_total, num_seqs);
  } else {
    tail_kernel<<<1, 64, 0, stream>>>(cu, num_seqs, tail, nullptr, 0);
    dim3 grid((unsigned)total_out, NH, 2);
    kvc_naive<<<grid, HD, 0, stream>>>(kp, vp, wk, wv, cu, num_seqs, out, out_half);
  }
}

// Round 3
// 382.625 us; speedup vs baseline: 1.3207x; 1.0519x over previous
//
#include <hip/hip_runtime.h>

#define NH 4
#define HD 128
#define BS 32
#define STRIDE 16

typedef float  floatx4 __attribute__((ext_vector_type(4)));
typedef __bf16 bf16x8  __attribute__((ext_vector_type(8)));
typedef __bf16 bf16x2  __attribute__((ext_vector_type(2)));
typedef unsigned short u16x8 __attribute__((ext_vector_type(8)));

__device__ __forceinline__ unsigned short f2bf(float f) {
  unsigned u = __builtin_bit_cast(unsigned, f);
  u += 0x7FFFu + ((u >> 16) & 1u);   // RTNE (inputs finite)
  return (unsigned short)(u >> 16);
}

__device__ __forceinline__ bf16x8 cvt8(float4 lo, float4 hi) {
  bf16x8 r;
#if __has_builtin(__builtin_amdgcn_cvt_pk_bf16_f32)
  bf16x2 p0 = __builtin_bit_cast(bf16x2, __builtin_amdgcn_cvt_pk_bf16_f32(lo.x, lo.y));
  bf16x2 p1 = __builtin_bit_cast(bf16x2, __builtin_amdgcn_cvt_pk_bf16_f32(lo.z, lo.w));
  bf16x2 p2 = __builtin_bit_cast(bf16x2, __builtin_amdgcn_cvt_pk_bf16_f32(hi.x, hi.y));
  bf16x2 p3 = __builtin_bit_cast(bf16x2, __builtin_amdgcn_cvt_pk_bf16_f32(hi.z, hi.w));
  r[0] = p0[0]; r[1] = p0[1]; r[2] = p1[0]; r[3] = p1[1];
  r[4] = p2[0]; r[5] = p2[1]; r[6] = p3[0]; r[7] = p3[1];
#else
  u16x8 t;
  t[0] = f2bf(lo.x); t[1] = f2bf(lo.y); t[2] = f2bf(lo.z); t[3] = f2bf(lo.w);
  t[4] = f2bf(hi.x); t[5] = f2bf(hi.y); t[6] = f2bf(hi.z); t[7] = f2bf(hi.w);
  r = __builtin_bit_cast(bf16x8, t);
#endif
  return r;
}

__device__ __forceinline__ void gld16(const unsigned short* g, unsigned short* l) {
  __builtin_amdgcn_global_load_lds(
      (const __attribute__((address_space(1))) unsigned int*)(g),
      (__attribute__((address_space(3))) unsigned int*)(l), 16, 0, 0);
}

// Prep: LDS-tiled transpose of w into wt layout [mat][j][k0][fq][e][dq] (bf16),
// so B staging is 1KB-contiguous per chunk and ds_read_b128 frags are
// 2-way-bank aliased (free). Block 256 = one (mat,j,k0) tile. Block 256 (last)
// writes the cu_out prefix-sum tail (output 2).
__global__ void prep_kernel(const float* __restrict__ wk, const float* __restrict__ wv,
                            unsigned short* __restrict__ wt,
                            const int* __restrict__ cu, int num_seqs,
                            float* __restrict__ tail) {
  const int bx = blockIdx.x;
  if (bx == 2 * BS * 4) {
    if (threadIdx.x == 0) {
      int acc = 0;
      tail[0] = 0.0f;
      for (int b = 0; b < num_seqs; ++b) {
        int n = cu[b + 1] - cu[b];
        acc += (n - BS) / STRIDE;
        tail[b + 1] = (float)acc;
      }
    }
    return;
  }
  const int mat = bx >> 7;
  const int j   = (bx >> 2) & 31;
  const int k0  = bx & 3;
  const float* __restrict__ w =
      (mat ? wv : wk) + (size_t)j * (HD * HD) + (size_t)k0 * 32 * HD;
  __shared__ unsigned short tile[32][HD];
  const int t = threadIdx.x;
  const int r = t >> 3, c = (t & 7) * 16;
#pragma unroll
  for (int i = 0; i < 16; i += 4) {
    float4 f = *(const float4*)(w + r * HD + c + i);
    tile[r][c + i + 0] = f2bf(f.x);
    tile[r][c + i + 1] = f2bf(f.y);
    tile[r][c + i + 2] = f2bf(f.z);
    tile[r][c + i + 3] = f2bf(f.w);
  }
  __syncthreads();
  unsigned short* dst =
      wt + (size_t)mat * (BS * HD * HD) + (size_t)j * 16384 + k0 * 4096;
#pragma unroll
  for (int it = 0; it < 2; ++it) {
    int fi = t + it * 256;      // 0..511 over (fq, e)
    int fq = fi >> 7, e = fi & 127;
    u16x8 fr;
#pragma unroll
    for (int dq = 0; dq < 8; ++dq) fr[dq] = tile[fq * 8 + dq][e];
    *(u16x8*)(dst + fq * 1024 + e * 8) = fr;
  }
}

// Main GEMM. Block = 32m x 128n (4 waves: wave w -> msub=(w&1)*16, eh=(w>>1)*64).
// B double-buffered in LDS via global_load_lds (buf0=h0 halves, buf1=h1 halves,
// compile-time parity). A in registers, prefetched one j ahead via parity arrays.
__global__ __launch_bounds__(256, 4) void kvc_gemm(
    const float* __restrict__ kp, const float* __restrict__ vp,
    const unsigned short* __restrict__ wt, const int* __restrict__ cu,
    float* __restrict__ out, long out_half, int M_total, int num_seqs) {

  __shared__ unsigned short Bs[2][8192];   // 2 x 16 KB stages

  const int mat = blockIdx.y;
  const float* __restrict__ x = mat ? vp : kp;
  const unsigned short* __restrict__ wmat = wt + (size_t)mat * (BS * HD * HD);
  float* __restrict__ outp = out + (size_t)mat * out_half;

  const int tid = threadIdx.x, wid = tid >> 6, lane = tid & 63;
  const int fl = lane & 15, fq = lane >> 4;
  const int msub = (wid & 1) * 16;
  const int ehw  = (wid >> 1) * 64;
  const int mbase = blockIdx.x * 32 + msub;

  // m -> (o,h) -> token base (inline cu_out scan; num_seqs small)
  int m = mbase + fl;
  int mc = m < M_total ? m : M_total - 1;
  int o = mc >> 2, h = mc & 3;
  int tb = 0, accb = 0;
  for (int b = 0; b < num_seqs; ++b) {
    int c0 = cu[b], c1 = cu[b + 1];
    int ol = (c1 - c0 - BS) / STRIDE;
    if (o >= accb && o - accb < ol) tb = c0 + (o - accb) * STRIDE;
    accb += ol;
  }
  const float* __restrict__ arow = x + ((size_t)tb * NH + h) * HD + fq * 8;

  floatx4 acc[4];
#pragma unroll
  for (int ni = 0; ni < 4; ++ni) acc[ni] = (floatx4){0.f, 0.f, 0.f, 0.f};

  float4 a[2][8];

#define ALOAD(JN, P)                                                        \
  {                                                                         \
    const float* ar_ = arow + (size_t)(JN) * (NH * HD);                     \
    _Pragma("unroll") for (int k0_ = 0; k0_ < 4; ++k0_) {                   \
      a[P][2 * k0_]     = *(const float4*)(ar_ + k0_ * 32);                 \
      a[P][2 * k0_ + 1] = *(const float4*)(ar_ + k0_ * 32 + 4);             \
    }                                                                       \
  }

  // Stage half H of column j: 16KB = 16 chunks of 1KB; wave stages 4 chunks.
#define BSTAGE(J, H, P)                                                     \
  {                                                                         \
    const unsigned short* s_ =                                              \
        wmat + (size_t)(J) * 16384 + (H) * 8192 + wid * 2048 + lane * 8;    \
    _Pragma("unroll") for (int i_ = 0; i_ < 4; ++i_)                        \
        gld16(s_ + i_ * 512, &Bs[P][wid * 2048 + i_ * 512]);                \
  }

  // Compute k0 = KB, KB+1 from buffer P with A parity PA.
#define CPH(PA, P, KB)                                                      \
  {                                                                         \
    _Pragma("unroll") for (int k0l_ = 0; k0l_ < 2; ++k0l_) {                \
      const int k0_ = (KB) + k0l_;                                          \
      bf16x8 af_ = cvt8(a[PA][2 * k0_], a[PA][2 * k0_ + 1]);                \
      _Pragma("unroll") for (int ni_ = 0; ni_ < 4; ++ni_) {                 \
        bf16x8 bf_ = *(const bf16x8*)&Bs[P][k0l_ * 4096 + fq * 1024 +       \
                                           (ehw + ni_ * 16 + fl) * 8];      \
        acc[ni_] = __builtin_amdgcn_mfma_f32_16x16x32_bf16(                 \
            af_, bf_, acc[ni_], 0, 0, 0);                                   \
      }                                                                     \
    }                                                                       \
  }

#define JBODY(J, PA)                                                        \
  {                                                                         \
    __syncthreads();              /* (J,h0) staged into buf0 is ready */    \
    BSTAGE(J, 1, 1);              /* stage (J,h1) -> buf1 */                \
    if ((J) + 1 < BS) ALOAD((J) + 1, PA ^ 1);                               \
    CPH(PA, 0, 0);                                                          \
    __syncthreads();              /* (J,h1) ready */                        \
    if ((J) + 1 < BS) BSTAGE((J) + 1, 0, 0);  /* (J+1,h0) -> buf0 */        \
    CPH(PA, 1, 2);                                                          \
  }

  BSTAGE(0, 0, 0);
  ALOAD(0, 0);
  for (int j = 0; j < BS; j += 2) {
    JBODY(j, 0);
    JBODY(j + 1, 1);
  }
#undef JBODY
#undef CPH
#undef BSTAGE
#undef ALOAD

  // C/D: col = lane&15 (= e offset fl), row = fq*4 + reg
#pragma unroll
  for (int ni = 0; ni < 4; ++ni) {
#pragma unroll
    for (int r = 0; r < 4; ++r) {
      const int mg = mbase + fq * 4 + r;
      if (mg < M_total) outp[(size_t)mg * HD + ehw + ni * 16 + fl] = acc[ni][r];
    }
  }
}

// Fallback path if ws is too small for the weight transpose.
__global__ void tail_kernel(const int* __restrict__ cu, int num_seqs,
                            float* __restrict__ tail) {
  if (threadIdx.x == 0) {
    int acc = 0;
    tail[0] = 0.0f;
    for (int b = 0; b < num_seqs; ++b) {
      int n = cu[b + 1] - cu[b];
      acc += (n - BS) / STRIDE;
      tail[b + 1] = (float)acc;
    }
  }
}

__global__ void kvc_naive(const float* __restrict__ kp, const float* __restrict__ vp,
                          const float* __restrict__ wk, const float* __restrict__ wv,
                          const int* __restrict__ cu, int num_seqs,
                          float* __restrict__ out, long out_half) {
  int o = blockIdx.x, h = blockIdx.y, mat = blockIdx.z;
  int e = threadIdx.x;
  int acc = 0, base = -1;
  for (int b = 0; b < num_seqs; ++b) {
    int n = cu[b + 1] - cu[b];
    int ol = (n - BS) / STRIDE;
    if (o < acc + ol) { base = cu[b] + (o - acc) * STRIDE; break; }
    acc += ol;
  }
  if (base < 0) return;
  const float* x = mat ? vp : kp;
  const float* w = mat ? wv : wk;
  float s = 0.f;
  for (int j = 0; j < BS; ++j)
    for (int d = 0; d < HD; ++d)
      s += x[(size_t)(base + j) * (NH * HD) + h * HD + d] * w[(j * HD + d) * HD + e];
  out[(size_t)mat * out_half + ((size_t)o * NH + h) * HD + e] = s;
}

extern "C" void kernel_launch(void* const* d_in, const int* in_sizes, int n_in,
                              void* d_out, int out_size, void* d_ws, size_t ws_size,
                              hipStream_t stream) {
  const float* kp = (const float*)d_in[0];
  const float* vp = (const float*)d_in[1];
  const float* wk = (const float*)d_in[2];
  const float* wv = (const float*)d_in[3];
  const int* cu = (const int*)d_in[4];
  const int num_seqs = in_sizes[4] - 1;
  float* out = (float*)d_out;

  const long total_out = ((long)out_size - (num_seqs + 1)) / (2L * NH * HD);
  const long out_half = total_out * NH * HD;
  const int M_total = (int)(total_out * NH);
  float* tail = out + 2 * out_half;

  const size_t need_ws = (size_t)2 * BS * HD * HD * sizeof(unsigned short);
  if (ws_size >= need_ws) {
    unsigned short* wt = (unsigned short*)d_ws;
    prep_kernel<<<2 * BS * 4 + 1, 256, 0, stream>>>(wk, wv, wt, cu, num_seqs, tail);
    dim3 grid((M_total + 31) / 32, 2);
    kvc_gemm<<<grid, 256, 0, stream>>>(kp, vp, wt, cu, out, out_half, M_total,
                                       num_seqs);
  } else {
    tail_kernel<<<1, 64, 0, stream>>>(cu, num_seqs, tail);
    dim3 grid((unsigned)total_out, NH, 2);
    kvc_naive<<<grid, HD, 0, stream>>>(kp, vp, wk, wv, cu, num_seqs, out, out_half);
  }
}